// Round 2
// baseline (1622.225 us; speedup 1.0000x reference)
//
#include <hip/hip_runtime.h>
#include <hip/hip_bf16.h>
#include <cstdint>
#include <cmath>

// B=512, S=13 (7 sparse + 6 numeric), D=1024, H=16, HD=64, DFF=4096, L=4
// M = B*S = 6656 tokens = 52 * 128 (exact 128-tile multiple)

typedef __bf16 bf16x8 __attribute__((ext_vector_type(8)));
typedef float  f32x4  __attribute__((ext_vector_type(4)));

// async global->LDS, 16B per lane (HW: wave-uniform base + lane*16)
__device__ __forceinline__ void async16(void* lds, const void* g) {
  __builtin_amdgcn_global_load_lds(
      (const __attribute__((address_space(1))) unsigned int*)g,
      (__attribute__((address_space(3))) unsigned int*)lds, 16, 0, 0);
}

// ---- fp32 -> bf16, 8 elems/thread ----
__global__ __launch_bounds__(256) void f2b_kernel(const float* __restrict__ s,
                                                  __bf16* __restrict__ d, int n8) {
  int i = blockIdx.x * 256 + threadIdx.x;
  if (i >= n8) return;
  const float4* s4 = (const float4*)s;
  float4 a = s4[2 * i], b = s4[2 * i + 1];
  bf16x8 o;
  o[0] = (__bf16)a.x; o[1] = (__bf16)a.y; o[2] = (__bf16)a.z; o[3] = (__bf16)a.w;
  o[4] = (__bf16)b.x; o[5] = (__bf16)b.y; o[6] = (__bf16)b.z; o[7] = (__bf16)b.w;
  *(bf16x8*)(d + (size_t)i * 8) = o;
}

// ---- build x0: [6656,1024] (sparse embeds + thermometer numeric enc) ----
__global__ __launch_bounds__(256) void build_x_kernel(
    const int* __restrict__ sparse, const int* __restrict__ numeric,
    const float* __restrict__ semb, const float* __restrict__ nemb,
    float* __restrict__ xf, __bf16* __restrict__ xb) {
  int r = blockIdx.x;
  int b = r / 13, s = r % 13;
  int t = threadIdx.x;
  size_t base = (size_t)r * 1024;
  if (s < 7) {
    int tok = sparse[b * 7 + s];
    const float* src = semb + (size_t)tok * 1024;
    for (int d = t; d < 1024; d += 256) {
      float v = src[d];
      xf[base + d] = v; xb[base + d] = (__bf16)v;
    }
  } else {
    int j = s - 7;
    float nv = (float)numeric[b * 6 + j];
    float scaled = nv * (j < 2 ? 1.0f : 512.0f / 100000.0f);
    for (int d = t; d < 1024; d += 256) {
      float v;
      if (d < 512) v = fminf(fmaxf(scaled - (float)d, 0.0f), 1.0f);
      else         v = nemb[j * 512 + (d - 512)];
      xf[base + d] = v; xb[base + d] = (__bf16)v;
    }
  }
}

// ---- GEMM: C[M,N] = A[M,K] * W[N,K]^T + bias ----
// EPI: 0 -> fp32 out, 1 -> bf16 out, 2 -> exact-gelu + bf16 out
// 128x128 tile, BK=32, 256 thr (2x2 waves of 64x64), mfma_f32_16x16x32_bf16
template <int EPI>
__global__ __launch_bounds__(256) void gemm_bt(
    const __bf16* __restrict__ A, const __bf16* __restrict__ Bw,
    const float* __restrict__ bias, float* __restrict__ Cf,
    __bf16* __restrict__ Cb, int N, int K) {
  __shared__ __attribute__((aligned(16))) __bf16 As[128 * 32];
  __shared__ __attribute__((aligned(16))) __bf16 Bs[128 * 32];
  const int t = threadIdx.x;
  const int bm = blockIdx.x, bn = blockIdx.y;
  const int lane = t & 63, wid = t >> 6;
  const int wm = (wid >> 1) << 6, wn = (wid & 1) << 6;
  const int lm = lane & 15, lq = lane >> 4;
  const int arow = t >> 2, acol = (t & 3) << 3;  // rows 0..63 cols (t&3)*8
  const __bf16* Ag = A + (size_t)(bm * 128 + arow) * K + acol;
  const __bf16* Bg = Bw + (size_t)(bn * 128 + arow) * K + acol;
  const size_t half = (size_t)64 * K;            // rows 64..127
  const __bf16* a_rd = As + (wm + lm) * 32 + lq * 8;
  const __bf16* b_rd = Bs + (wn + lm) * 32 + lq * 8;
  f32x4 acc[4][4] = {};
  for (int k0 = 0; k0 < K; k0 += 32) {
    __syncthreads();                 // prior-iter LDS reads complete
    async16(As + t * 8,        Ag);
    async16(As + 2048 + t * 8, Ag + half);
    async16(Bs + t * 8,        Bg);
    async16(Bs + 2048 + t * 8, Bg + half);
    Ag += 32; Bg += 32;
    asm volatile("s_waitcnt vmcnt(0)" ::: "memory");
    __syncthreads();
    bf16x8 af[4], bf[4];
#pragma unroll
    for (int i = 0; i < 4; i++) af[i] = *(const bf16x8*)(a_rd + i * 16 * 32);
#pragma unroll
    for (int i = 0; i < 4; i++) bf[i] = *(const bf16x8*)(b_rd + i * 16 * 32);
#pragma unroll
    for (int mi = 0; mi < 4; mi++)
#pragma unroll
      for (int ni = 0; ni < 4; ni++)
        acc[mi][ni] = __builtin_amdgcn_mfma_f32_16x16x32_bf16(af[mi], bf[ni], acc[mi][ni], 0, 0, 0);
  }
  // C/D layout: col=lane&15, row=(lane>>4)*4+reg  [m89/m91 verified]
  const int row0 = bm * 128 + wm + lq * 4;
  const int col0 = bn * 128 + wn + lm;
#pragma unroll
  for (int mi = 0; mi < 4; mi++) {
#pragma unroll
    for (int ni = 0; ni < 4; ni++) {
      int col = col0 + ni * 16;
      float bv = bias[col];
#pragma unroll
      for (int r = 0; r < 4; r++) {
        int row = row0 + mi * 16 + r;
        float v = acc[mi][ni][r] + bv;
        if (EPI == 2) v = v * 0.5f * (1.0f + erff(v * 0.70710678118f));
        if (EPI == 0) Cf[(size_t)row * N + col] = v;
        else          Cb[(size_t)row * N + col] = (__bf16)v;
      }
    }
  }
}

// ---- attention: one wave per (b,h); S=13, HD=64; fp32 in LDS ----
__global__ __launch_bounds__(64) void attn_kernel(const __bf16* __restrict__ qkv,
                                                  __bf16* __restrict__ o) {
  int bh = blockIdx.x;
  int b = bh >> 4, h = bh & 15;
  int lane = threadIdx.x;
  __shared__ float qs[13][68], ks[13][68], vs[13][68];
  __shared__ float S[13][16];
  const __bf16* base = qkv + (size_t)b * 13 * 3072 + h * 64 + lane;
#pragma unroll
  for (int i = 0; i < 13; i++) {
    qs[i][lane] = (float)base[(size_t)i * 3072];
    ks[i][lane] = (float)base[(size_t)i * 3072 + 1024];
    vs[i][lane] = (float)base[(size_t)i * 3072 + 2048];
  }
  __syncthreads();
  for (int rep = 0; rep < 3; rep++) {
    int idx = lane + rep * 64;
    if (idx < 169) {
      int i = idx / 13, j = idx % 13;
      float s = 0.f;
#pragma unroll
      for (int d = 0; d < 64; d++) s += qs[i][d] * ks[j][d];
      S[i][j] = s * 0.125f;
    }
  }
  __syncthreads();
  if (lane < 13) {
    float m = S[lane][0];
#pragma unroll
    for (int j = 1; j < 13; j++) m = fmaxf(m, S[lane][j]);
    float sum = 0.f;
#pragma unroll
    for (int j = 0; j < 13; j++) { float e = expf(S[lane][j] - m); S[lane][j] = e; sum += e; }
    float inv = 1.0f / sum;
#pragma unroll
    for (int j = 0; j < 13; j++) S[lane][j] *= inv;
  }
  __syncthreads();
  __bf16* ob = o + (size_t)b * 13 * 1024 + h * 64 + lane;
#pragma unroll
  for (int i = 0; i < 13; i++) {
    float s = 0.f;
#pragma unroll
    for (int j = 0; j < 13; j++) s += S[i][j] * vs[j][lane];
    ob[(size_t)i * 1024] = (__bf16)s;
  }
}

// ---- fused residual add + LayerNorm (D=1024) ----
__global__ __launch_bounds__(256) void add_ln_kernel(
    const float* __restrict__ xin, const float* __restrict__ delta,
    const float* __restrict__ g, const float* __restrict__ bta,
    float* __restrict__ xf_out, __bf16* __restrict__ xb_out) {
  int r = blockIdx.x, t = threadIdx.x;
  size_t base = (size_t)r * 1024;
  float vals[4], s = 0.f, s2 = 0.f;
#pragma unroll
  for (int i = 0; i < 4; i++) {
    int d = t + i * 256;
    float v = xin[base + d] + delta[base + d];
    vals[i] = v; s += v; s2 += v * v;
  }
  __shared__ float red[8];
  for (int off = 32; off > 0; off >>= 1) { s += __shfl_down(s, off); s2 += __shfl_down(s2, off); }
  if ((t & 63) == 0) { red[t >> 6] = s; red[4 + (t >> 6)] = s2; }
  __syncthreads();
  float S1 = red[0] + red[1] + red[2] + red[3];
  float S2 = red[4] + red[5] + red[6] + red[7];
  float mean = S1 * (1.0f / 1024.0f);
  float var  = S2 * (1.0f / 1024.0f) - mean * mean;
  float inv  = rsqrtf(var + 1e-5f);
#pragma unroll
  for (int i = 0; i < 4; i++) {
    int d = t + i * 256;
    float y = (vals[i] - mean) * inv * g[d] + bta[d];
    xf_out[base + d] = y;
    xb_out[base + d] = (__bf16)y;
  }
}

extern "C" void kernel_launch(void* const* d_in, const int* in_sizes, int n_in,
                              void* d_out, int out_size, void* d_ws, size_t ws_size,
                              hipStream_t stream) {
  const int*   sparse  = (const int*)d_in[0];
  const int*   numeric = (const int*)d_in[1];
  const float* semb    = (const float*)d_in[2];
  const float* nemb    = (const float*)d_in[3];
  const float* Wqkv    = (const float*)d_in[4];
  const float* bqkv    = (const float*)d_in[5];
  const float* Wo      = (const float*)d_in[6];
  const float* bo      = (const float*)d_in[7];
  const float* W1      = (const float*)d_in[8];
  const float* b1      = (const float*)d_in[9];
  const float* W2      = (const float*)d_in[10];
  const float* b2      = (const float*)d_in[11];
  const float* ln1g    = (const float*)d_in[12];
  const float* ln1b    = (const float*)d_in[13];
  const float* ln2g    = (const float*)d_in[14];
  const float* ln2b    = (const float*)d_in[15];
  float* out = (float*)d_out;

  // ---- workspace layout: ~99 MB total ----
  char* ws = (char*)d_ws;
  size_t off = 0;
  auto carve = [&](size_t bytes) -> char* {
    char* p = ws + off; off += (bytes + 255) & ~(size_t)255; return p;
  };
  __bf16* wb   = (__bf16*)carve((size_t)4096 * 1024 * 2);        //  8.4 MB weight scratch
  float*  xf   = (float*) carve((size_t)6656 * 1024 * 4);        // 27.3 MB fp32 residual
  __bf16* xb   = (__bf16*)carve((size_t)6656 * 1024 * 2);        // 13.6 MB bf16 x
  char*   pool = carve((size_t)6656 * 4096 * 2);                  // 54.6 MB (qkv+attn | h)
  __bf16* qkvb  = (__bf16*)pool;
  __bf16* attnb = (__bf16*)(pool + (size_t)6656 * 3072 * 2);
  __bf16* hb    = (__bf16*)pool;
  float*  tmpf  = out;  // d_out doubles as fp32 GEMM-delta scratch (safe: add_ln
                        // reads its row into regs before writing the same row)

  build_x_kernel<<<6656, 256, 0, stream>>>(sparse, numeric, semb, nemb, xf, xb);

  for (int l = 0; l < 4; ++l) {
    // qkv = x @ Wqkv^T + bqkv
    f2b_kernel<<<1536, 256, 0, stream>>>(Wqkv + (size_t)l * 3145728, wb, 393216);
    gemm_bt<1><<<dim3(52, 24), 256, 0, stream>>>(xb, wb, bqkv + l * 3072, nullptr, qkvb, 3072, 1024);
    attn_kernel<<<8192, 64, 0, stream>>>(qkvb, attnb);
    // o = attn @ Wo^T + bo
    f2b_kernel<<<512, 256, 0, stream>>>(Wo + (size_t)l * 1048576, wb, 131072);
    gemm_bt<0><<<dim3(52, 8), 256, 0, stream>>>(attnb, wb, bo + l * 1024, tmpf, nullptr, 1024, 1024);
    add_ln_kernel<<<6656, 256, 0, stream>>>(xf, tmpf, ln1g + l * 1024, ln1b + l * 1024, xf, xb);
    // h = gelu(x @ W1^T + b1)
    f2b_kernel<<<2048, 256, 0, stream>>>(W1 + (size_t)l * 4194304, wb, 524288);
    gemm_bt<2><<<dim3(52, 32), 256, 0, stream>>>(xb, wb, b1 + l * 4096, nullptr, hb, 4096, 1024);
    // ff = h @ W2^T + b2
    f2b_kernel<<<2048, 256, 0, stream>>>(W2 + (size_t)l * 4194304, wb, 524288);
    gemm_bt<0><<<dim3(52, 8), 256, 0, stream>>>(hb, wb, b2 + l * 1024, tmpf, nullptr, 1024, 4096);
    float* xdst = (l == 3) ? out : xf;
    add_ln_kernel<<<6656, 256, 0, stream>>>(xf, tmpf, ln2g + l * 1024, ln2b + l * 1024, xdst, xb);
  }
}

// Round 3
// 1439.315 us; speedup vs baseline: 1.1271x; 1.1271x over previous
//
#include <hip/hip_runtime.h>
#include <hip/hip_bf16.h>
#include <cstdint>
#include <cmath>

// B=512, S=13, D=1024, H=16, HD=64, DFF=4096, L=4;  M = 6656 = 52*128

typedef __bf16 bf16x8 __attribute__((ext_vector_type(8)));
typedef float  f32x4  __attribute__((ext_vector_type(4)));

__device__ __forceinline__ void async16(void* lds, const void* g) {
  __builtin_amdgcn_global_load_lds(
      (const __attribute__((address_space(1))) unsigned int*)g,
      (__attribute__((address_space(3))) unsigned int*)lds, 16, 0, 0);
}

// ---- fp32 -> bf16, 8 elems/thread ----
__global__ __launch_bounds__(256) void f2b_kernel(const float* __restrict__ s,
                                                  __bf16* __restrict__ d, int n8) {
  int i = blockIdx.x * 256 + threadIdx.x;
  if (i >= n8) return;
  const float4* s4 = (const float4*)s;
  float4 a = s4[2 * i], b = s4[2 * i + 1];
  bf16x8 o;
  o[0] = (__bf16)a.x; o[1] = (__bf16)a.y; o[2] = (__bf16)a.z; o[3] = (__bf16)a.w;
  o[4] = (__bf16)b.x; o[5] = (__bf16)b.y; o[6] = (__bf16)b.z; o[7] = (__bf16)b.w;
  *(bf16x8*)(d + (size_t)i * 8) = o;
}

// two-region variant (Wqkv + Wo in one launch)
__global__ __launch_bounds__(256) void f2b2_kernel(
    const float* __restrict__ s0, __bf16* __restrict__ d0, int n0,
    const float* __restrict__ s1, __bf16* __restrict__ d1, int n8) {
  int i = blockIdx.x * 256 + threadIdx.x;
  if (i >= n8) return;
  const float* s; __bf16* d; int j;
  if (i < n0) { s = s0; d = d0; j = i; } else { s = s1; d = d1; j = i - n0; }
  const float4* s4 = (const float4*)s;
  float4 a = s4[2 * j], b = s4[2 * j + 1];
  bf16x8 o;
  o[0] = (__bf16)a.x; o[1] = (__bf16)a.y; o[2] = (__bf16)a.z; o[3] = (__bf16)a.w;
  o[4] = (__bf16)b.x; o[5] = (__bf16)b.y; o[6] = (__bf16)b.z; o[7] = (__bf16)b.w;
  *(bf16x8*)(d + (size_t)j * 8) = o;
}

// ---- build x0 ----
__global__ __launch_bounds__(256) void build_x_kernel(
    const int* __restrict__ sparse, const int* __restrict__ numeric,
    const float* __restrict__ semb, const float* __restrict__ nemb,
    float* __restrict__ xf, __bf16* __restrict__ xb) {
  int r = blockIdx.x;
  int b = r / 13, s = r % 13;
  int t = threadIdx.x;
  size_t base = (size_t)r * 1024;
  if (s < 7) {
    int tok = sparse[b * 7 + s];
    const float* src = semb + (size_t)tok * 1024;
    for (int d = t; d < 1024; d += 256) {
      float v = src[d];
      xf[base + d] = v; xb[base + d] = (__bf16)v;
    }
  } else {
    int j = s - 7;
    float nv = (float)numeric[b * 6 + j];
    float scaled = nv * (j < 2 ? 1.0f : 512.0f / 100000.0f);
    for (int d = t; d < 1024; d += 256) {
      float v;
      if (d < 512) v = fminf(fmaxf(scaled - (float)d, 0.0f), 1.0f);
      else         v = nemb[j * 512 + (d - 512)];
      xf[base + d] = v; xb[base + d] = (__bf16)v;
    }
  }
}

// ---- GEMM: C[M,N] = A[M,K] * W[N,K]^T + bias ----
// EPI: 0 fp32 out, 1 bf16 out, 2 gelu+bf16 out
// 128x128 tile, BK=64, 256 thr (2x2 waves of 64x64), mfma_f32_16x16x32_bf16
// LDS XOR swizzle: physical chunk p of row r holds global k-chunk (p ^ (r&7));
// fragment read pc = c ^ (lm&7) spreads 16 lanes over all 8 bank groups (2/grp = free)
template <int EPI>
__global__ __launch_bounds__(256) void gemm_bt(
    const __bf16* __restrict__ A, const __bf16* __restrict__ Bw,
    const float* __restrict__ bias, float* __restrict__ Cf,
    __bf16* __restrict__ Cb, int N, int K) {
  __shared__ __attribute__((aligned(16))) __bf16 As[128 * 64];
  __shared__ __attribute__((aligned(16))) __bf16 Bs[128 * 64];
  const int t = threadIdx.x;
  const int bm = blockIdx.x, bn = blockIdx.y;
  const int lane = t & 63, wid = t >> 6;
  const int wm = (wid >> 1) << 6, wn = (wid & 1) << 6;
  const int lm = lane & 15, lq = lane >> 4;
  // staging: thread t -> physical slot (row = t>>3, p = t&7), +32 rows per round
  const int srow = t >> 3, sp = t & 7;
  const int sc = sp ^ (srow & 7);            // global chunk (round-invariant: 32%8==0)
  const __bf16* Ag = A + (size_t)(bm * 128 + srow) * K + sc * 8;
  const __bf16* Bg = Bw + (size_t)(bn * 128 + srow) * K + sc * 8;
  const size_t rstep = (size_t)32 * K;
  f32x4 acc[4][4] = {};
  const int nIter = K >> 6;
  for (int k0 = 0; k0 < nIter; ++k0) {
    __syncthreads();
#pragma unroll
    for (int r = 0; r < 4; ++r) {
      async16(As + r * 2048 + t * 8, Ag + r * rstep);
      async16(Bs + r * 2048 + t * 8, Bg + r * rstep);
    }
    Ag += 64; Bg += 64;
    asm volatile("s_waitcnt vmcnt(0)" ::: "memory");
    __syncthreads();
#pragma unroll
    for (int kk = 0; kk < 2; ++kk) {
      bf16x8 af[4], bf[4];
#pragma unroll
      for (int i = 0; i < 4; i++) {
        int row = wm + i * 16 + lm;
        int pc = ((kk << 2) + lq) ^ (lm & 7);
        af[i] = *(const bf16x8*)(As + row * 64 + pc * 8);
      }
#pragma unroll
      for (int i = 0; i < 4; i++) {
        int row = wn + i * 16 + lm;
        int pc = ((kk << 2) + lq) ^ (lm & 7);
        bf[i] = *(const bf16x8*)(Bs + row * 64 + pc * 8);
      }
#pragma unroll
      for (int mi = 0; mi < 4; mi++)
#pragma unroll
        for (int ni = 0; ni < 4; ni++)
          acc[mi][ni] = __builtin_amdgcn_mfma_f32_16x16x32_bf16(af[mi], bf[ni], acc[mi][ni], 0, 0, 0);
    }
  }
  // C/D layout: col=lane&15, row=(lane>>4)*4+reg
  const int row0 = bm * 128 + wm + lq * 4;
  const int col0 = bn * 128 + wn + lm;
#pragma unroll
  for (int mi = 0; mi < 4; mi++) {
#pragma unroll
    for (int ni = 0; ni < 4; ni++) {
      int col = col0 + ni * 16;
      float bv = bias[col];
#pragma unroll
      for (int r = 0; r < 4; r++) {
        int row = row0 + mi * 16 + r;
        float v = acc[mi][ni][r] + bv;
        if (EPI == 2) {
          // tanh-form gelu (max dev vs erf-gelu ~3e-3), exp-based tanh, rcp div
          float u = fabsf(v);
          float y = 0.7978845608f * u * (1.0f + 0.044715f * u * u);
          float e = __expf(-2.0f * y);
          float th = (1.0f - e) * __builtin_amdgcn_rcpf(1.0f + e);  // tanh(y) >= 0
          v = 0.5f * v * (1.0f + (v < 0.0f ? -th : th));
        }
        if (EPI == 0) Cf[(size_t)row * N + col] = v;
        else          Cb[(size_t)row * N + col] = (__bf16)v;
      }
    }
  }
}

// ---- attention: one wave per (b,h); S=13, HD=64 ----
__global__ __launch_bounds__(64) void attn_kernel(const __bf16* __restrict__ qkv,
                                                  __bf16* __restrict__ o) {
  int bh = blockIdx.x;
  int b = bh >> 4, h = bh & 15;
  int lane = threadIdx.x;
  __shared__ float qs[13][68], ks[13][68], vs[13][68];
  __shared__ float S[13][16];
  const __bf16* base = qkv + (size_t)b * 13 * 3072 + h * 64 + lane;
#pragma unroll
  for (int i = 0; i < 13; i++) {
    qs[i][lane] = (float)base[(size_t)i * 3072];
    ks[i][lane] = (float)base[(size_t)i * 3072 + 1024];
    vs[i][lane] = (float)base[(size_t)i * 3072 + 2048];
  }
  __syncthreads();
  for (int rep = 0; rep < 3; rep++) {
    int idx = lane + rep * 64;
    if (idx < 169) {
      int i = idx / 13, j = idx % 13;
      float s = 0.f;
#pragma unroll
      for (int d = 0; d < 64; d++) s += qs[i][d] * ks[j][d];
      S[i][j] = s * 0.125f;
    }
  }
  __syncthreads();
  if (lane < 13) {
    float m = S[lane][0];
#pragma unroll
    for (int j = 1; j < 13; j++) m = fmaxf(m, S[lane][j]);
    float sum = 0.f;
#pragma unroll
    for (int j = 0; j < 13; j++) { float e = expf(S[lane][j] - m); S[lane][j] = e; sum += e; }
    float inv = 1.0f / sum;
#pragma unroll
    for (int j = 0; j < 13; j++) S[lane][j] *= inv;
  }
  __syncthreads();
  __bf16* ob = o + (size_t)b * 13 * 1024 + h * 64 + lane;
#pragma unroll
  for (int i = 0; i < 13; i++) {
    float s = 0.f;
#pragma unroll
    for (int j = 0; j < 13; j++) s += S[i][j] * vs[j][lane];
    ob[(size_t)i * 1024] = (__bf16)s;
  }
}

// ---- fused residual add + LayerNorm (D=1024) ----
__global__ __launch_bounds__(256) void add_ln_kernel(
    const float* __restrict__ xin, const float* __restrict__ delta,
    const float* __restrict__ g, const float* __restrict__ bta,
    float* __restrict__ xf_out, __bf16* __restrict__ xb_out) {
  int r = blockIdx.x, t = threadIdx.x;
  size_t base = (size_t)r * 1024;
  float vals[4], s = 0.f, s2 = 0.f;
#pragma unroll
  for (int i = 0; i < 4; i++) {
    int d = t + i * 256;
    float v = xin[base + d] + delta[base + d];
    vals[i] = v; s += v; s2 += v * v;
  }
  __shared__ float red[8];
  for (int off = 32; off > 0; off >>= 1) { s += __shfl_down(s, off); s2 += __shfl_down(s2, off); }
  if ((t & 63) == 0) { red[t >> 6] = s; red[4 + (t >> 6)] = s2; }
  __syncthreads();
  float S1 = red[0] + red[1] + red[2] + red[3];
  float S2 = red[4] + red[5] + red[6] + red[7];
  float mean = S1 * (1.0f / 1024.0f);
  float var  = S2 * (1.0f / 1024.0f) - mean * mean;
  float inv  = rsqrtf(var + 1e-5f);
#pragma unroll
  for (int i = 0; i < 4; i++) {
    int d = t + i * 256;
    float y = (vals[i] - mean) * inv * g[d] + bta[d];
    xf_out[base + d] = y;
    xb_out[base + d] = (__bf16)y;
  }
}

extern "C" void kernel_launch(void* const* d_in, const int* in_sizes, int n_in,
                              void* d_out, int out_size, void* d_ws, size_t ws_size,
                              hipStream_t stream) {
  const int*   sparse  = (const int*)d_in[0];
  const int*   numeric = (const int*)d_in[1];
  const float* semb    = (const float*)d_in[2];
  const float* nemb    = (const float*)d_in[3];
  const float* Wqkv    = (const float*)d_in[4];
  const float* bqkv    = (const float*)d_in[5];
  const float* Wo      = (const float*)d_in[6];
  const float* bo      = (const float*)d_in[7];
  const float* W1      = (const float*)d_in[8];
  const float* b1      = (const float*)d_in[9];
  const float* W2      = (const float*)d_in[10];
  const float* b2      = (const float*)d_in[11];
  const float* ln1g    = (const float*)d_in[12];
  const float* ln1b    = (const float*)d_in[13];
  const float* ln2g    = (const float*)d_in[14];
  const float* ln2b    = (const float*)d_in[15];
  float* out = (float*)d_out;

  char* ws = (char*)d_ws;
  size_t off = 0;
  auto carve = [&](size_t bytes) -> char* {
    char* p = ws + off; off += (bytes + 255) & ~(size_t)255; return p;
  };
  __bf16* wb   = (__bf16*)carve((size_t)4096 * 1024 * 2);   //  8.4 MB weight scratch
  float*  xf   = (float*) carve((size_t)6656 * 1024 * 4);   // 27.3 MB fp32 residual
  __bf16* xb   = (__bf16*)carve((size_t)6656 * 1024 * 2);   // 13.6 MB bf16 x
  char*   pool = carve((size_t)6656 * 4096 * 2);            // 54.6 MB (qkv+attn | h)
  __bf16* qkvb  = (__bf16*)pool;
  __bf16* attnb = (__bf16*)(pool + (size_t)6656 * 3072 * 2);
  __bf16* hb    = (__bf16*)pool;
  float*  tmpf  = out;  // d_out doubles as fp32 GEMM-delta scratch

  build_x_kernel<<<6656, 256, 0, stream>>>(sparse, numeric, semb, nemb, xf, xb);

  for (int l = 0; l < 4; ++l) {
    // Wqkv + Wo -> bf16 (exactly fills wb: 3145728 + 1048576 = 4194304 elems)
    f2b2_kernel<<<2048, 256, 0, stream>>>(Wqkv + (size_t)l * 3145728, wb, 393216,
                                          Wo + (size_t)l * 1048576, wb + 3145728, 524288);
    gemm_bt<1><<<dim3(52, 24), 256, 0, stream>>>(xb, wb, bqkv + l * 3072, nullptr, qkvb, 3072, 1024);
    attn_kernel<<<8192, 64, 0, stream>>>(qkvb, attnb);
    gemm_bt<0><<<dim3(52, 8), 256, 0, stream>>>(attnb, wb + 3145728, bo + l * 1024, tmpf, nullptr, 1024, 1024);
    add_ln_kernel<<<6656, 256, 0, stream>>>(xf, tmpf, ln1g + l * 1024, ln1b + l * 1024, xf, xb);
    f2b_kernel<<<2048, 256, 0, stream>>>(W1 + (size_t)l * 4194304, wb, 524288);
    gemm_bt<2><<<dim3(52, 32), 256, 0, stream>>>(xb, wb, b1 + l * 4096, nullptr, hb, 4096, 1024);
    f2b_kernel<<<2048, 256, 0, stream>>>(W2 + (size_t)l * 4194304, wb, 524288);
    gemm_bt<0><<<dim3(52, 8), 256, 0, stream>>>(hb, wb, b2 + l * 1024, tmpf, nullptr, 1024, 4096);
    float* xdst = (l == 3) ? out : xf;
    add_ln_kernel<<<6656, 256, 0, stream>>>(xf, tmpf, ln2g + l * 1024, ln2b + l * 1024, xdst, xb);
  }
}

// Round 4
// 1382.740 us; speedup vs baseline: 1.1732x; 1.0409x over previous
//
#include <hip/hip_runtime.h>
#include <hip/hip_bf16.h>
#include <cstdint>
#include <cmath>

// B=512, S=13, D=1024, H=16, HD=64, DFF=4096, L=4;  M = 6656 = 52*128 = 104*64

typedef __bf16 bf16x8 __attribute__((ext_vector_type(8)));
typedef float  f32x4  __attribute__((ext_vector_type(4)));

__device__ __forceinline__ void async16(void* lds, const void* g) {
  __builtin_amdgcn_global_load_lds(
      (const __attribute__((address_space(1))) unsigned int*)g,
      (__attribute__((address_space(3))) unsigned int*)lds, 16, 0, 0);
}

__device__ __forceinline__ float gelu_f(float v) {
  // tanh-form gelu (max dev vs erf-gelu ~3e-3), exp-based tanh, rcp div
  float u = fabsf(v);
  float y = 0.7978845608f * u * (1.0f + 0.044715f * u * u);
  float e = __expf(-2.0f * y);
  float th = (1.0f - e) * __builtin_amdgcn_rcpf(1.0f + e);
  return 0.5f * v * (1.0f + (v < 0.0f ? -th : th));
}

// ---- fp32 -> bf16, 8 elems/thread ----
__global__ __launch_bounds__(256) void f2b_kernel(const float* __restrict__ s,
                                                  __bf16* __restrict__ d, int n8) {
  int i = blockIdx.x * 256 + threadIdx.x;
  if (i >= n8) return;
  const float4* s4 = (const float4*)s;
  float4 a = s4[2 * i], b = s4[2 * i + 1];
  bf16x8 o;
  o[0] = (__bf16)a.x; o[1] = (__bf16)a.y; o[2] = (__bf16)a.z; o[3] = (__bf16)a.w;
  o[4] = (__bf16)b.x; o[5] = (__bf16)b.y; o[6] = (__bf16)b.z; o[7] = (__bf16)b.w;
  *(bf16x8*)(d + (size_t)i * 8) = o;
}

__global__ __launch_bounds__(256) void f2b2_kernel(
    const float* __restrict__ s0, __bf16* __restrict__ d0, int n0,
    const float* __restrict__ s1, __bf16* __restrict__ d1, int n8) {
  int i = blockIdx.x * 256 + threadIdx.x;
  if (i >= n8) return;
  const float* s; __bf16* d; int j;
  if (i < n0) { s = s0; d = d0; j = i; } else { s = s1; d = d1; j = i - n0; }
  const float4* s4 = (const float4*)s;
  float4 a = s4[2 * j], b = s4[2 * j + 1];
  bf16x8 o;
  o[0] = (__bf16)a.x; o[1] = (__bf16)a.y; o[2] = (__bf16)a.z; o[3] = (__bf16)a.w;
  o[4] = (__bf16)b.x; o[5] = (__bf16)b.y; o[6] = (__bf16)b.z; o[7] = (__bf16)b.w;
  *(bf16x8*)(d + (size_t)j * 8) = o;
}

// ---- build x0 ----
__global__ __launch_bounds__(256) void build_x_kernel(
    const int* __restrict__ sparse, const int* __restrict__ numeric,
    const float* __restrict__ semb, const float* __restrict__ nemb,
    float* __restrict__ xf, __bf16* __restrict__ xb) {
  int r = blockIdx.x;
  int b = r / 13, s = r % 13;
  int t = threadIdx.x;
  size_t base = (size_t)r * 1024;
  if (s < 7) {
    int tok = sparse[b * 7 + s];
    const float* src = semb + (size_t)tok * 1024;
    for (int d = t; d < 1024; d += 256) {
      float v = src[d];
      xf[base + d] = v; xb[base + d] = (__bf16)v;
    }
  } else {
    int j = s - 7;
    float nv = (float)numeric[b * 6 + j];
    float scaled = nv * (j < 2 ? 1.0f : 512.0f / 100000.0f);
    for (int d = t; d < 1024; d += 256) {
      float v;
      if (d < 512) v = fminf(fmaxf(scaled - (float)d, 0.0f), 1.0f);
      else         v = nemb[j * 512 + (d - 512)];
      xf[base + d] = v; xb[base + d] = (__bf16)v;
    }
  }
}

// ---- WIDE GEMM: block 128x256, 4 waves, wave tile 128x64 (acc 8x4) ----
// C[M,N] = A[M,K] * W[N,K]^T + bias.  EPI: 1 bf16 out, 2 gelu+bf16 out
// LDS XOR swizzle: physical chunk p of row r holds global chunk p ^ (r&7).
template <int EPI>
__global__ __launch_bounds__(256, 2) void gemm_wide(
    const __bf16* __restrict__ A, const __bf16* __restrict__ Bw,
    const float* __restrict__ bias, __bf16* __restrict__ Cb, int N, int K) {
  __shared__ __attribute__((aligned(16))) __bf16 As[128 * 64];
  __shared__ __attribute__((aligned(16))) __bf16 Bs[256 * 64];
  const int t = threadIdx.x;
  const int bm = blockIdx.x, bn = blockIdx.y;
  const int lane = t & 63, wid = t >> 6;
  const int wn = wid << 6;
  const int lm = lane & 15, lq = lane >> 4;
  const int srow = t >> 3, sp = t & 7;
  const int sc = sp ^ (srow & 7);          // row&7 invariant per 32-row step
  const __bf16* Ag = A + (size_t)(bm * 128 + srow) * K + sc * 8;
  const __bf16* Bg = Bw + (size_t)(bn * 256 + srow) * K + sc * 8;
  const size_t rstep = (size_t)32 * K;
  f32x4 acc[8][4] = {};
  const int nIter = K >> 6;
  for (int k0 = 0; k0 < nIter; ++k0) {
    __syncthreads();
#pragma unroll
    for (int r = 0; r < 4; ++r) async16(As + r * 2048 + t * 8, Ag + r * rstep);
#pragma unroll
    for (int r = 0; r < 8; ++r) async16(Bs + r * 2048 + t * 8, Bg + r * rstep);
    Ag += 64; Bg += 64;
    asm volatile("s_waitcnt vmcnt(0)" ::: "memory");
    __syncthreads();
#pragma unroll
    for (int kk = 0; kk < 2; ++kk) {
      const int pc = ((kk << 2) + lq) ^ (lm & 7);
      bf16x8 af[8], bf[4];
#pragma unroll
      for (int i = 0; i < 8; i++) af[i] = *(const bf16x8*)(As + (i * 16 + lm) * 64 + pc * 8);
#pragma unroll
      for (int i = 0; i < 4; i++) bf[i] = *(const bf16x8*)(Bs + (wn + i * 16 + lm) * 64 + pc * 8);
#pragma unroll
      for (int mi = 0; mi < 8; mi++)
#pragma unroll
        for (int ni = 0; ni < 4; ni++)
          acc[mi][ni] = __builtin_amdgcn_mfma_f32_16x16x32_bf16(af[mi], bf[ni], acc[mi][ni], 0, 0, 0);
    }
  }
  const int row0 = bm * 128 + lq * 4;
  const int col0 = bn * 256 + wn + lm;
#pragma unroll
  for (int mi = 0; mi < 8; mi++) {
#pragma unroll
    for (int ni = 0; ni < 4; ni++) {
      int col = col0 + ni * 16;
      float bv = bias[col];
#pragma unroll
      for (int r = 0; r < 4; r++) {
        int row = row0 + mi * 16 + r;
        float v = acc[mi][ni][r] + bv;
        if (EPI == 2) v = gelu_f(v);
        Cb[(size_t)row * N + col] = (__bf16)v;
      }
    }
  }
}

// ---- NARROW GEMM: block 64x128, 2 waves (128 thr), wave tile 64x64, fp32 out ----
__global__ __launch_bounds__(128, 4) void gemm_narrow(
    const __bf16* __restrict__ A, const __bf16* __restrict__ Bw,
    const float* __restrict__ bias, float* __restrict__ Cf, int N, int K) {
  __shared__ __attribute__((aligned(16))) __bf16 As[64 * 64];
  __shared__ __attribute__((aligned(16))) __bf16 Bs[128 * 64];
  const int t = threadIdx.x;
  const int bm = blockIdx.x, bn = blockIdx.y;
  const int lane = t & 63, wid = t >> 6;
  const int wn = wid << 6;
  const int lm = lane & 15, lq = lane >> 4;
  const int srow = t >> 3, sp = t & 7;     // srow 0..15
  const int sc = sp ^ (srow & 7);          // 16-row step keeps row&7 invariant
  const __bf16* Ag = A + (size_t)(bm * 64 + srow) * K + sc * 8;
  const __bf16* Bg = Bw + (size_t)(bn * 128 + srow) * K + sc * 8;
  const size_t rstep = (size_t)16 * K;
  f32x4 acc[4][4] = {};
  const int nIter = K >> 6;
  for (int k0 = 0; k0 < nIter; ++k0) {
    __syncthreads();
#pragma unroll
    for (int r = 0; r < 4; ++r) async16(As + r * 1024 + t * 8, Ag + r * rstep);
#pragma unroll
    for (int r = 0; r < 8; ++r) async16(Bs + r * 1024 + t * 8, Bg + r * rstep);
    Ag += 64; Bg += 64;
    asm volatile("s_waitcnt vmcnt(0)" ::: "memory");
    __syncthreads();
#pragma unroll
    for (int kk = 0; kk < 2; ++kk) {
      const int pc = ((kk << 2) + lq) ^ (lm & 7);
      bf16x8 af[4], bf[4];
#pragma unroll
      for (int i = 0; i < 4; i++) af[i] = *(const bf16x8*)(As + (i * 16 + lm) * 64 + pc * 8);
#pragma unroll
      for (int i = 0; i < 4; i++) bf[i] = *(const bf16x8*)(Bs + (wn + i * 16 + lm) * 64 + pc * 8);
#pragma unroll
      for (int mi = 0; mi < 4; mi++)
#pragma unroll
        for (int ni = 0; ni < 4; ni++)
          acc[mi][ni] = __builtin_amdgcn_mfma_f32_16x16x32_bf16(af[mi], bf[ni], acc[mi][ni], 0, 0, 0);
    }
  }
  const int row0 = bm * 64 + lq * 4;
  const int col0 = bn * 128 + wn + lm;
#pragma unroll
  for (int mi = 0; mi < 4; mi++) {
#pragma unroll
    for (int ni = 0; ni < 4; ni++) {
      int col = col0 + ni * 16;
      float bv = bias[col];
#pragma unroll
      for (int r = 0; r < 4; r++) {
        int row = row0 + mi * 16 + r;
        Cf[(size_t)row * N + col] = acc[mi][ni][r] + bv;
      }
    }
  }
}

// ---- attention: one wave per (b,h); S=13, HD=64 ----
__global__ __launch_bounds__(64) void attn_kernel(const __bf16* __restrict__ qkv,
                                                  __bf16* __restrict__ o) {
  int bh = blockIdx.x;
  int b = bh >> 4, h = bh & 15;
  int lane = threadIdx.x;
  __shared__ float qs[13][68], ks[13][68], vs[13][68];
  __shared__ float S[13][16];
  const __bf16* base = qkv + (size_t)b * 13 * 3072 + h * 64 + lane;
#pragma unroll
  for (int i = 0; i < 13; i++) {
    qs[i][lane] = (float)base[(size_t)i * 3072];
    ks[i][lane] = (float)base[(size_t)i * 3072 + 1024];
    vs[i][lane] = (float)base[(size_t)i * 3072 + 2048];
  }
  __syncthreads();
  for (int rep = 0; rep < 3; rep++) {
    int idx = lane + rep * 64;
    if (idx < 169) {
      int i = idx / 13, j = idx % 13;
      float s = 0.f;
#pragma unroll
      for (int d = 0; d < 64; d++) s += qs[i][d] * ks[j][d];
      S[i][j] = s * 0.125f;
    }
  }
  __syncthreads();
  if (lane < 13) {
    float m = S[lane][0];
#pragma unroll
    for (int j = 1; j < 13; j++) m = fmaxf(m, S[lane][j]);
    float sum = 0.f;
#pragma unroll
    for (int j = 0; j < 13; j++) { float e = expf(S[lane][j] - m); S[lane][j] = e; sum += e; }
    float inv = 1.0f / sum;
#pragma unroll
    for (int j = 0; j < 13; j++) S[lane][j] *= inv;
  }
  __syncthreads();
  __bf16* ob = o + (size_t)b * 13 * 1024 + h * 64 + lane;
#pragma unroll
  for (int i = 0; i < 13; i++) {
    float s = 0.f;
#pragma unroll
    for (int j = 0; j < 13; j++) s += S[i][j] * vs[j][lane];
    ob[(size_t)i * 1024] = (__bf16)s;
  }
}

// ---- fused residual add + LayerNorm (D=1024) ----
__global__ __launch_bounds__(256) void add_ln_kernel(
    const float* __restrict__ xin, const float* __restrict__ delta,
    const float* __restrict__ g, const float* __restrict__ bta,
    float* __restrict__ xf_out, __bf16* __restrict__ xb_out) {
  int r = blockIdx.x, t = threadIdx.x;
  size_t base = (size_t)r * 1024;
  float vals[4], s = 0.f, s2 = 0.f;
#pragma unroll
  for (int i = 0; i < 4; i++) {
    int d = t + i * 256;
    float v = xin[base + d] + delta[base + d];
    vals[i] = v; s += v; s2 += v * v;
  }
  __shared__ float red[8];
  for (int off = 32; off > 0; off >>= 1) { s += __shfl_down(s, off); s2 += __shfl_down(s2, off); }
  if ((t & 63) == 0) { red[t >> 6] = s; red[4 + (t >> 6)] = s2; }
  __syncthreads();
  float S1 = red[0] + red[1] + red[2] + red[3];
  float S2 = red[4] + red[5] + red[6] + red[7];
  float mean = S1 * (1.0f / 1024.0f);
  float var  = S2 * (1.0f / 1024.0f) - mean * mean;
  float inv  = rsqrtf(var + 1e-5f);
#pragma unroll
  for (int i = 0; i < 4; i++) {
    int d = t + i * 256;
    float y = (vals[i] - mean) * inv * g[d] + bta[d];
    xf_out[base + d] = y;
    xb_out[base + d] = (__bf16)y;
  }
}

extern "C" void kernel_launch(void* const* d_in, const int* in_sizes, int n_in,
                              void* d_out, int out_size, void* d_ws, size_t ws_size,
                              hipStream_t stream) {
  const int*   sparse  = (const int*)d_in[0];
  const int*   numeric = (const int*)d_in[1];
  const float* semb    = (const float*)d_in[2];
  const float* nemb    = (const float*)d_in[3];
  const float* Wqkv    = (const float*)d_in[4];
  const float* bqkv    = (const float*)d_in[5];
  const float* Wo      = (const float*)d_in[6];
  const float* bo      = (const float*)d_in[7];
  const float* W1      = (const float*)d_in[8];
  const float* b1      = (const float*)d_in[9];
  const float* W2      = (const float*)d_in[10];
  const float* b2      = (const float*)d_in[11];
  const float* ln1g    = (const float*)d_in[12];
  const float* ln1b    = (const float*)d_in[13];
  const float* ln2g    = (const float*)d_in[14];
  const float* ln2b    = (const float*)d_in[15];
  float* out = (float*)d_out;

  char* ws = (char*)d_ws;
  size_t off = 0;
  auto carve = [&](size_t bytes) -> char* {
    char* p = ws + off; off += (bytes + 255) & ~(size_t)255; return p;
  };
  __bf16* wb   = (__bf16*)carve((size_t)4096 * 1024 * 2);   //  8.4 MB weight scratch
  float*  xf   = (float*) carve((size_t)6656 * 1024 * 4);   // 27.3 MB fp32 residual
  __bf16* xb   = (__bf16*)carve((size_t)6656 * 1024 * 2);   // 13.6 MB bf16 x
  char*   pool = carve((size_t)6656 * 4096 * 2);            // 54.6 MB (qkv+attn | h)
  __bf16* qkvb  = (__bf16*)pool;
  __bf16* attnb = (__bf16*)(pool + (size_t)6656 * 3072 * 2);
  __bf16* hb    = (__bf16*)pool;
  float*  tmpf  = out;  // d_out doubles as fp32 GEMM-delta scratch

  build_x_kernel<<<6656, 256, 0, stream>>>(sparse, numeric, semb, nemb, xf, xb);

  for (int l = 0; l < 4; ++l) {
    f2b2_kernel<<<2048, 256, 0, stream>>>(Wqkv + (size_t)l * 3145728, wb, 393216,
                                          Wo + (size_t)l * 1048576, wb + 3145728, 524288);
    gemm_wide<1><<<dim3(52, 12), 256, 0, stream>>>(xb, wb, bqkv + l * 3072, qkvb, 3072, 1024);
    attn_kernel<<<8192, 64, 0, stream>>>(qkvb, attnb);
    gemm_narrow<<<dim3(104, 8), 128, 0, stream>>>(attnb, wb + 3145728, bo + l * 1024, tmpf, 1024, 1024);
    add_ln_kernel<<<6656, 256, 0, stream>>>(xf, tmpf, ln1g + l * 1024, ln1b + l * 1024, xf, xb);
    f2b_kernel<<<2048, 256, 0, stream>>>(W1 + (size_t)l * 4194304, wb, 524288);
    gemm_wide<2><<<dim3(52, 16), 256, 0, stream>>>(xb, wb, b1 + l * 4096, hb, 4096, 1024);
    f2b_kernel<<<2048, 256, 0, stream>>>(W2 + (size_t)l * 4194304, wb, 524288);
    gemm_narrow<<<dim3(104, 8), 128, 0, stream>>>(hb, wb, b2 + l * 1024, tmpf, 1024, 4096);
    float* xdst = (l == 3) ? out : xf;
    add_ln_kernel<<<6656, 256, 0, stream>>>(xf, tmpf, ln2g + l * 1024, ln2b + l * 1024, xdst, xb);
  }
}